// Round 8
// baseline (282.715 us; speedup 1.0000x reference)
//
#include <hip/hip_runtime.h>

// FlashMultiHeadAttention on MI355X (gfx950), bf16-MFMA pipeline.
// B=4 T=2048 D=512 H=8 DK=64. All matmuls via v_mfma_f32_16x16x32_bf16.
// Fragment trick: A and B operands use symmetric lane maps (row/col = lane&15,
// k-slots = (lane>>4, j)); any k-slot bijection psi is valid as long as A and
// B of the SAME mfma use the same psi (summation-order permutation).
// C/D layout (HW-verified per guide): col = lane&15, row = (lane>>4)*4 + reg.
//
// QKV GEMM epilogue fuses the l2-norm (wave's 64 cols = one (proj,head);
// row-norm = Sigma_j + shfl_xor(1,2,4,8)). Q scaled by SCALE*log2e/||q||.
//
// Attention: swapped QK^T (A=K, B=Q) -> lane holds a full q-row of P.
// PV: in-register P fragments; V stored FRAGMENT-MAJOR with
// psi_pv(g,j) = {g*4+j (j<4), 16+g*4+(j-4)} -> one 16B load per fragment.
// MASKING IS MATRIX-IZED: masked V rows are zeroed in k_vt (numerator =
// reference's exp(-10000-max)=0 semantics) and the softmax denominator is
// one extra MFMA against a ones-column fragment (col0 = 1_unmasked bf16,
// cols1-15 = 0, same psi_pv) -> D[q][0] = Sigma_s P[q][s]*1[s], fp32-
// accumulated over the SAME bf16 P as the numerator. No mask, no cndmask,
// no scalar denominator adds in the inner loop. den[g*4+r] lands at lane
// g*16 reg r (C-layout col0) -> 4 shfls at the end.
// QBLK=128 (8 waves/block): waves share K/V tiles (L1), halving L2 traffic.
//
// Numerics: Q,K are L2-normalized => |score*SCALE| <= 0.125, so clip(+-10)
// is a no-op and softmax needs no max-subtract (exp2 arg in [-0.19,0.19]).

#define B_  4
#define T_  2048
#define D_  512
#define H_  8
#define DK_ 64
#define BT_ (B_*T_)

typedef unsigned short u16;
typedef unsigned char u8;
typedef u16 u16x8 __attribute__((ext_vector_type(8)));
typedef u16 u16x4 __attribute__((ext_vector_type(4)));
typedef __bf16 bf16x8 __attribute__((ext_vector_type(8)));
typedef float f32x4 __attribute__((ext_vector_type(4)));

__device__ inline u16 f2bf(float f) {
  return __builtin_bit_cast(u16, (__bf16)f);  // RNE; compiler can pack pairs
}
__device__ inline float bf2f(u16 v) {
  return __builtin_bit_cast(float, (unsigned)v << 16);
}
__device__ inline f32x4 mfma16(u16x8 a, u16x8 b, f32x4 c) {
  return __builtin_amdgcn_mfma_f32_16x16x32_bf16(
      __builtin_bit_cast(bf16x8, a), __builtin_bit_cast(bf16x8, b), c, 0, 0, 0);
}

// ---------------- mask detect + normalize + ones-table ----------
// The reference mask is a bool array; the harness may hand it to us as
// int32, raw uint8 bytes, or int64. Every block re-derives the dtype flag
// from the first 8KB (safe to read under every candidate layout):
//   any word > 1            -> uint8  (int32/int64 words are only 0/1)
//   else all odd words == 0 -> int64  (P(coincidence under int32) ~ 2^-1024)
//   else                    -> int32
// Outputs: m32[b*T+t] in {0,1}, and Vones bf16 fragment-major
// [b][t>>5][g'][j'] = (mask ? 0 : 1.0), with psi(g',j') = t&31 (inverse-psi
// scatter: tl<16 -> g'=tl>>2,j'=tl&3; else u=tl-16, g'=u>>2, j'=4+(u&3)).
__global__ __launch_bounds__(256) void k_mask(const unsigned* __restrict__ mw,
                                              const u8* __restrict__ mb,
                                              int* __restrict__ out,
                                              u16* __restrict__ vones) {
  __shared__ unsigned sb[2];
  int tid = threadIdx.x;
  if (tid == 0) { sb[0] = 0; sb[1] = 0; }
  __syncthreads();
  unsigned big = 0, odd = 0;
  for (int i = tid; i < 2048; i += 256) {
    unsigned v = mw[i];
    big |= (v > 1u) ? 1u : 0u;
    if (i & 1) odd |= (v != 0u) ? 1u : 0u;
  }
  if (big) atomicOr(&sb[0], 1u);
  if (odd) atomicOr(&sb[1], 1u);
  __syncthreads();
  int fl = sb[0] ? 1 : (sb[1] ? 0 : 2);
  int i = blockIdx.x * 256 + tid;
  unsigned v = (fl == 1) ? (unsigned)mb[i] : (fl == 2) ? mw[2 * i] : mw[i];
  int m = (v != 0u) ? 1 : 0;
  out[i] = m;
  int b = i >> 11, t = i & (T_ - 1);
  int tl = t & 31;
  int gp, jp;
  if (tl < 16) { gp = tl >> 2; jp = tl & 3; }
  else { int u = tl - 16; gp = u >> 2; jp = 4 + (u & 3); }
  vones[((b * (T_ / 32) + (t >> 5)) * 4 + gp) * 8 + jp] = m ? (u16)0 : (u16)0x3F80;
}

// ---------------- fp32 -> bf16 convert, both weight tensors ----------------
__global__ __launch_bounds__(256) void k_cvt(const float* __restrict__ s1,
                                             u16* __restrict__ d1, int n1,
                                             const float* __restrict__ s2,
                                             u16* __restrict__ d2, int n2) {
  int i = (blockIdx.x * 256 + threadIdx.x) * 4;
  const float* s;
  u16* d;
  if (i < n1) {
    s = s1 + i; d = d1 + i;
  } else {
    int j = i - n1;
    if (j >= n2) return;
    s = s2 + j; d = d2 + j;
  }
  float4 v = *(const float4*)s;
  u16x4 o = {f2bf(v.x), f2bf(v.y), f2bf(v.z), f2bf(v.w)};
  *(u16x4*)d = o;
}

// ---------------- LayerNorm -> bf16 ----------------
__global__ __launch_bounds__(256) void k_ln(const float* __restrict__ x,
                                            const float* __restrict__ gg,
                                            const float* __restrict__ bb,
                                            u16* __restrict__ xn) {
  int wave = threadIdx.x >> 6, lane = threadIdx.x & 63;
  size_t row = (size_t)blockIdx.x * 4 + wave;
  const float* xr = x + row * D_ + lane * 8;
  float v[8];
  *(float4*)(v)     = *(const float4*)(xr);
  *(float4*)(v + 4) = *(const float4*)(xr + 4);
  float s = 0.f;
#pragma unroll
  for (int i = 0; i < 8; i++) s += v[i];
#pragma unroll
  for (int o = 1; o < 64; o <<= 1) s += __shfl_xor(s, o);
  float mu = s * (1.0f / 512.0f);
  float vs = 0.f;
#pragma unroll
  for (int i = 0; i < 8; i++) { float t = v[i] - mu; vs += t * t; }
#pragma unroll
  for (int o = 1; o < 64; o <<= 1) vs += __shfl_xor(vs, o);
  float rs = rsqrtf(vs * (1.0f / 512.0f) + 1e-6f);
  float gv[8], bv[8];
  *(float4*)(gv)     = *(const float4*)(gg + lane * 8);
  *(float4*)(gv + 4) = *(const float4*)(gg + lane * 8 + 4);
  *(float4*)(bv)     = *(const float4*)(bb + lane * 8);
  *(float4*)(bv + 4) = *(const float4*)(bb + lane * 8 + 4);
  u16x8 o;
#pragma unroll
  for (int i = 0; i < 8; i++) o[i] = f2bf((v[i] - mu) * rs * gv[i] + bv[i]);
  *(u16x8*)(xn + row * D_ + lane * 8) = o;
}

// ---------------- bf16 GEMM: C[M,N] = A[M,K] * Bt[N,K]^T, +bias ----
// MODE 0: fp32 store, (acc+bias)*oscale  (out-projection).
// MODE 1: fused QKV epilogue — per-row l2norm over the wave's 64 cols
//         (= one (proj,head)); Q scaled by SCALE*log2e/||q||, K by 1/||k||,
//         V raw; scatter bf16 to Qs/Ks/Vq in [bh][t][dk] layout.
// 128x128 tile, BK=32, 4 waves (2x2), 64x64 per wave. LDS row stride 40
// ushorts (80 B) -> <=2-way bank conflicts on both staging and frag reads.
// Register prefetch: next k-tile's global loads issue before the MFMA
// cluster so their latency hides under compute (T14-lite, m249).
template <int MODE>
__global__ __launch_bounds__(256) void k_gemm(const u16* __restrict__ A,
                                              const u16* __restrict__ Bt,
                                              const float* __restrict__ bias,
                                              float* __restrict__ Cf,
                                              u16* __restrict__ Qs,
                                              u16* __restrict__ Ks,
                                              u16* __restrict__ Vq,
                                              int M, int N, int K, float oscale) {
  __shared__ u16 lA[128 * 40];
  __shared__ u16 lB[128 * 40];
  int tid = threadIdx.x;
  int lane = tid & 63, w = tid >> 6;
  int g = lane >> 4, l15 = lane & 15;
  int wm = (w >> 1) * 64, wn = (w & 1) * 64;
  size_t m0 = (size_t)blockIdx.x * 128, n0 = (size_t)blockIdx.y * 128;
  f32x4 acc[4][4] = {};
  int arow = tid >> 2, acol = (tid & 3) * 8;
  const u16* Ab = A + (m0 + arow) * K + acol;
  const u16* Bb = Bt + (n0 + arow) * K + acol;
  size_t step64 = (size_t)64 * K;
  u16x8 a0 = *(const u16x8*)(Ab);
  u16x8 a1 = *(const u16x8*)(Ab + step64);
  u16x8 b0 = *(const u16x8*)(Bb);
  u16x8 b1 = *(const u16x8*)(Bb + step64);
  for (int k0 = 0; k0 < K; k0 += 32) {
    *(u16x8*)(lA + arow * 40 + acol) = a0;
    *(u16x8*)(lA + (arow + 64) * 40 + acol) = a1;
    *(u16x8*)(lB + arow * 40 + acol) = b0;
    *(u16x8*)(lB + (arow + 64) * 40 + acol) = b1;
    __syncthreads();
    if (k0 + 32 < K) {  // prefetch next k-tile; waits land after the MFMAs
      a0 = *(const u16x8*)(Ab + k0 + 32);
      a1 = *(const u16x8*)(Ab + step64 + k0 + 32);
      b0 = *(const u16x8*)(Bb + k0 + 32);
      b1 = *(const u16x8*)(Bb + step64 + k0 + 32);
    }
    u16x8 af[4], bf[4];
#pragma unroll
    for (int i = 0; i < 4; i++)
      af[i] = *(const u16x8*)(lA + (wm + i * 16 + l15) * 40 + g * 8);
#pragma unroll
    for (int i = 0; i < 4; i++)
      bf[i] = *(const u16x8*)(lB + (wn + i * 16 + l15) * 40 + g * 8);
#pragma unroll
    for (int i = 0; i < 4; i++)
#pragma unroll
      for (int j = 0; j < 4; j++) acc[i][j] = mfma16(af[i], bf[j], acc[i][j]);
    __syncthreads();
  }
  if constexpr (MODE == 0) {
#pragma unroll
    for (int i = 0; i < 4; i++) {
      size_t row = m0 + wm + i * 16 + g * 4;
#pragma unroll
      for (int j = 0; j < 4; j++) {
        size_t col = n0 + wn + j * 16 + l15;
        float bs = bias[col];
#pragma unroll
        for (int r = 0; r < 4; r++)
          Cf[(row + r) * (size_t)N + col] = (acc[i][j][r] + bs) * oscale;
      }
    }
  } else {
    int base_col = (int)n0 + wn;            // multiple of 64: one (proj,head)
    int proj = base_col >> 9;               // 0=Q 1=K 2=V
    int hh = (base_col >> 6) & 7;
    u16* dbuf = (proj == 0) ? Qs : (proj == 1) ? Ks : Vq;
    float bs[4];
#pragma unroll
    for (int j = 0; j < 4; j++) bs[j] = bias[base_col + j * 16 + l15];
#pragma unroll
    for (int i = 0; i < 4; i++) {
      size_t row = m0 + wm + i * 16 + g * 4;
#pragma unroll
      for (int r = 0; r < 4; r++) {
        float v4[4];
        float s2 = 0.f;
#pragma unroll
        for (int j = 0; j < 4; j++) {
          float t = acc[i][j][r] + bs[j];
          v4[j] = t;
          s2 += t * t;
        }
        // sum over the 16 lanes sharing this output row (same g-group)
        s2 += __shfl_xor(s2, 1);
        s2 += __shfl_xor(s2, 2);
        s2 += __shfl_xor(s2, 4);
        s2 += __shfl_xor(s2, 8);
        float nrm = fmaxf(sqrtf(s2), 1e-8f);
        // 0.18033688 = SCALE(0.125) * log2(e); attn uses exp2
        float sc = (proj == 0) ? 0.18033688f / nrm
                 : (proj == 1) ? 1.0f / nrm : 1.0f;
        size_t rr = row + r;
        int bb_ = (int)(rr >> 11);
        int tt = (int)(rr & (T_ - 1));
        u16* dst = dbuf + ((size_t)(bb_ * H_ + hh) * T_ + tt) * 64;
#pragma unroll
        for (int j = 0; j < 4; j++) dst[j * 16 + l15] = f2bf(v4[j] * sc);
      }
    }
  }
}

// ---------------- V transpose -> fragment-major, masked rows zeroed --------
// Vq [bh][t][dk] -> Vf[((bh*(T/32)+sblk)*4+g)*64 + d][j=0..7] (u16x8 units),
// element j = V[t = sblk*32 + psi(g,j)][d] (zeroed if mask[b][t]),
// psi(g,j) = g*4+j (j<4), 16+g*4+(j-4) (j>=4) — the exact B-fragment k_attn
// feeds to PV, so each fragment is one coalesced 16B load there.
// Phase 2: d = lane (coalesced 1KB/wave stores), g = wave id (uniform).
__global__ __launch_bounds__(256) void k_vt(const u16* __restrict__ Vq,
                                            const int* __restrict__ m32,
                                            u16* __restrict__ Vf) {
  __shared__ u16 vt[64 * 66];
  int bh = blockIdx.x, t0 = blockIdx.y * 64;
  int b = bh >> 3;
  int u = threadIdx.x, tl = u >> 2, q = u & 3;
  const u16* src = Vq + ((size_t)bh * T_ + t0 + tl) * 64 + q * 16;
  u16x8 vr0 = *(const u16x8*)(src);
  u16x8 vr1 = *(const u16x8*)(src + 8);
  u16 keep = m32[b * T_ + t0 + tl] ? (u16)0 : (u16)0xFFFFu;
#pragma unroll
  for (int i = 0; i < 8; i++) { vr0[i] &= keep; vr1[i] &= keep; }
#pragma unroll
  for (int i = 0; i < 8; i++) {
    vt[(q * 16 + i) * 66 + tl] = vr0[i];      // vt[d][t_local]
    vt[(q * 16 + 8 + i) * 66 + tl] = vr1[i];
  }
  __syncthreads();
  int d = u & 63, gg = u >> 6;
#pragma unroll
  for (int sb = 0; sb < 2; sb++) {
    u16x8 o;
#pragma unroll
    for (int j = 0; j < 8; j++) {
      int psi = (j < 4) ? (gg * 4 + j) : (16 + gg * 4 + (j - 4));
      o[j] = vt[d * 66 + sb * 32 + psi];
    }
    size_t sblk = (size_t)(t0 >> 5) + sb;
    *(u16x8*)(Vf + ((((size_t)bh * (T_ / 32) + sblk) * 4 + gg) * 64 + d) * 8) = o;
  }
}

// ---------------- flash attention (swapped QK^T, all-register P) ----------
// Block: 512 thr = 8 waves, 128 q-rows (16/wave), s-tiles of 64. No LDS.
// All 8 waves consume the SAME K/V tiles per s-step (L1-resident).
// QK^T: mfma(A=K, B=Q) -> sa[nf][r] = S[s0+nf*16+g*4+r][q=l15].
// PV: in-register P fragments + fragment-major V (one 16B load each).
// Denominator: ones-column MFMA (accd); den[g*4+r] = accd[r] @ lane g*16.
// Mask is pre-baked into Vf (zeroed rows) and Vones. 4 heads/XCD swizzle.
__global__ __launch_bounds__(512) void k_attn(const u16* __restrict__ Qs,
                                              const u16* __restrict__ Ks,
                                              const u16* __restrict__ Vf,
                                              const u16* __restrict__ Vones,
                                              u16* __restrict__ AO) {
  int i = blockIdx.x;                       // 512 blocks = 8 XCD x 4 heads x 16
  int bh = (i & 7) * 4 + ((i >> 3) >> 4);   // 4 heads per XCD
  int t0 = ((i >> 3) & 15) * 128;
  int b = bh >> 3, h = bh & 7;
  int tid = threadIdx.x, w = tid >> 6, lane = tid & 63;
  int g = lane >> 4, l15 = lane & 15;
  // Q fragments (B-operand of QK^T): row t0+w*16+l15, dk slots g*8..+7 (+32)
  const u16* Qp = Qs + ((size_t)bh * T_ + t0 + w * 16 + l15) * 64 + g * 8;
  u16x8 bq0 = *(const u16x8*)(Qp);
  u16x8 bq1 = *(const u16x8*)(Qp + 32);
  const u16* Kb = Ks + (size_t)bh * T_ * 64;
  // fragment-major V base for this lane: + sblk*(4*64*8) + nd*16*8 per frag
  const u16* Vb = Vf + ((((size_t)bh * (T_ / 32)) * 4 + g) * 64 + l15) * 8;
  const u16* Ob = Vones + (size_t)b * (T_ / 32) * 32 + g * 8;
  f32x4 acc[4] = {};
  f32x4 accd = {};  // ones-column accumulator: den[g'*4+r] @ lane g'*16 reg r
  for (int s0 = 0; s0 < T_; s0 += 64) {
    f32x4 sa[4];
#pragma unroll
    for (int nf = 0; nf < 4; nf++) {
      const u16* kp = Kb + (size_t)(s0 + nf * 16 + l15) * 64 + g * 8;
      u16x8 k0 = *(const u16x8*)(kp);
      u16x8 k1 = *(const u16x8*)(kp + 32);
      f32x4 z = {0.f, 0.f, 0.f, 0.f};
      z = mfma16(k0, bq0, z);  // A=K (rows s), B=Q (cols q)
      z = mfma16(k1, bq1, z);
      sa[nf] = z;              // sa[nf][r] = S[s0+nf*16+g*4+r][l15] * log2e
    }
    // P = exp2(S') unconditionally (masked cols handled by zeroed V / Vones)
    u16 pb[4][4];
#pragma unroll
    for (int nf = 0; nf < 4; nf++)
#pragma unroll
      for (int r = 0; r < 4; r++) pb[nf][r] = f2bf(exp2f(sa[nf][r]));
    u16x8 pa0 = {pb[0][0], pb[0][1], pb[0][2], pb[0][3],
                 pb[1][0], pb[1][1], pb[1][2], pb[1][3]};
    u16x8 pa1 = {pb[2][0], pb[2][1], pb[2][2], pb[2][3],
                 pb[3][0], pb[3][1], pb[3][2], pb[3][3]};
    // ones-column B fragment: col0 (l15==0 lanes) = 1_unmasked, else 0
    u16x8 of0 = {}, of1 = {};
    if (l15 == 0) {
      of0 = *(const u16x8*)(Ob + (s0 >> 5) * 32);
      of1 = *(const u16x8*)(Ob + (s0 >> 5) * 32 + 32);
    }
    accd = mfma16(pa0, of0, accd);
    accd = mfma16(pa1, of1, accd);
    const u16* vs0 = Vb + (size_t)(s0 >> 5) * (4 * 64 * 8);
#pragma unroll
    for (int nd = 0; nd < 4; nd++) {
      u16x8 vf0 = *(const u16x8*)(vs0 + (size_t)nd * 16 * 8);
      u16x8 vf1 = *(const u16x8*)(vs0 + (size_t)(4 * 64 + nd * 16) * 8);
      acc[nd] = mfma16(pa0, vf0, acc[nd]);
      acc[nd] = mfma16(pa1, vf1, acc[nd]);
    }
  }
  // den for q-row g*4+r lives at lane g*16 (l15=0, g'=g), reg r
  float inv[4];
#pragma unroll
  for (int r = 0; r < 4; r++) inv[r] = 1.0f / __shfl(accd[r], g * 16);
#pragma unroll
  for (int r = 0; r < 4; r++) {
    size_t trow = (size_t)b * T_ + t0 + w * 16 + g * 4 + r;
#pragma unroll
    for (int nd = 0; nd < 4; nd++) {
      AO[trow * D_ + h * 64 + nd * 16 + l15] = f2bf(acc[nd][r] * inv[r]);
    }
  }
}

extern "C" void kernel_launch(void* const* d_in, const int* in_sizes, int n_in,
                              void* d_out, int out_size, void* d_ws, size_t ws_size,
                              hipStream_t stream) {
  (void)in_sizes; (void)n_in; (void)out_size; (void)ws_size;
  const float* x     = (const float*)d_in[0];
  const void*  maskp = d_in[1];
  const float* ln_g  = (const float*)d_in[2];
  const float* ln_b  = (const float*)d_in[3];
  const float* qkv_w = (const float*)d_in[4];
  const float* qkv_b = (const float*)d_in[5];
  const float* out_w = (const float*)d_in[6];
  const float* out_b = (const float*)d_in[7];

  char* ws = (char*)d_ws;
  size_t off = 0;
  auto alloc = [&](size_t bytes) -> void* {
    void* p = ws + off;
    off += (bytes + 255) & ~(size_t)255;
    return p;
  };
  u16*   xn   = (u16*)alloc((size_t)BT_ * D_ * 2);          // 8 MB
  u16*   qw   = (u16*)alloc((size_t)3 * D_ * D_ * 2);       // 1.5 MB
  u16*   ow   = (u16*)alloc((size_t)D_ * D_ * 2);           // 0.5 MB
  u16*   Vq   = (u16*)alloc((size_t)B_ * H_ * T_ * DK_ * 2);// 8 MB
  u16*   Vf   = (u16*)alloc((size_t)B_ * H_ * T_ * DK_ * 2);// 8 MB
  int*   m32  = (int*)alloc((size_t)BT_ * 4);               // 32 KB
  u16*   von  = (u16*)alloc((size_t)B_ * (T_ / 32) * 32 * 2);// 16 KB
  // Qs/Ks live in d_out (16 MB fp32 = exactly 2 x 8 MB bf16): fully written
  // by the fused QKV GEMM, dead before the final GEMM overwrites d_out.
  u16*   Qs   = (u16*)d_out;
  u16*   Ks   = Qs + (size_t)B_ * H_ * T_ * DK_;
  u16*   ao   = xn;  // xn is dead after the QKV GEMM; reuse for attn output

  k_mask<<<dim3(BT_ / 256), dim3(256), 0, stream>>>(
      (const unsigned*)maskp, (const u8*)maskp, m32, von);
  k_cvt<<<dim3(D_ * D_ / 256), dim3(256), 0, stream>>>(
      qkv_w, qw, 3 * D_ * D_, out_w, ow, D_ * D_);
  k_ln<<<dim3(BT_ / 4), dim3(256), 0, stream>>>(x, ln_g, ln_b, xn);
  k_gemm<1><<<dim3(BT_ / 128, 3 * D_ / 128), dim3(256), 0, stream>>>(
      xn, qw, qkv_b, nullptr, Qs, Ks, Vq, BT_, 3 * D_, D_, 1.0f);
  k_vt<<<dim3(B_ * H_, T_ / 64), dim3(256), 0, stream>>>(Vq, m32, Vf);
  k_attn<<<dim3(B_ * H_ * T_ / 128), dim3(512), 0, stream>>>(Qs, Ks, Vf, von, ao);
  k_gemm<0><<<dim3(BT_ / 128, D_ / 128), dim3(256), 0, stream>>>(
      ao, ow, out_b, (float*)d_out, nullptr, nullptr, nullptr, BT_, D_, D_, 0.5f);
}